// Round 10
// baseline (305.878 us; speedup 1.0000x reference)
//
#include <hip/hip_runtime.h>
#include <hip/hip_bf16.h>
#include <cmath>

typedef _Float16 f16x8 __attribute__((ext_vector_type(8)));
typedef _Float16 f16x4 __attribute__((ext_vector_type(4)));
typedef float f32x4 __attribute__((ext_vector_type(4)));
using h2_t = decltype(__builtin_amdgcn_cvt_pkrtz(0.f, 0.f));

#define T_SEQ 2048
#define C_DIM 768
#define H_NUM 12
#define NX (8192 * 768)
#define NW (768 * 768)

__device__ __forceinline__ unsigned short f2h(float f) {
    _Float16 h = (_Float16)f;
    return __builtin_bit_cast(unsigned short, h);
}

__device__ __forceinline__ float fexp2(float x) {
#if __has_builtin(__builtin_amdgcn_exp2f)
    return __builtin_amdgcn_exp2f(x);
#else
    return exp2f(x);
#endif
}

// build f16x4 from two packed half2
__device__ __forceinline__ f16x4 mk4(h2_t a, h2_t b) {
    uint2 u;
    u.x = __builtin_bit_cast(unsigned int, a);
    u.y = __builtin_bit_cast(unsigned int, b);
    return __builtin_bit_cast(f16x4, u);
}

// acc += d[0]*o[0] + d[1]*o[1]  (f16 mul, f32 acc) — softmax denom with SAME
// rounding as the PV numerator (sums the f16-rounded P values)
__device__ __forceinline__ float dot2acc(h2_t d, h2_t o, float acc) {
#if __has_builtin(__builtin_amdgcn_fdot2)
    return __builtin_amdgcn_fdot2(d, o, acc, false);
#else
    return acc + (float)d[0] + (float)d[1];
#endif
}

// async global->LDS 16B DMA
__device__ __forceinline__ void gld16(const unsigned short* g, unsigned short* l) {
    __builtin_amdgcn_global_load_lds(
        (const __attribute__((address_space(1))) unsigned int*)g,
        (__attribute__((address_space(3))) unsigned int*)l, 16, 0, 0);
}

// ---------------- prep: cast x (swizzled) + transpose-cast 4 weights ----------------
__global__ __launch_bounds__(256)
void prep(const float* __restrict__ x,
          const float* __restrict__ w0, const float* __restrict__ w1,
          const float* __restrict__ w2, const float* __restrict__ w3,
          unsigned short* __restrict__ xb, unsigned short* __restrict__ wt) {
    __shared__ float T[64][65];
    const int pid = blockIdx.x;
    if (pid < 3072) {
        int cidx = pid * 256 + threadIdx.x;
        int row = cidx / 96;
        int cp = cidx - row * 96;
        int dchunk = row * 96 + (cp & ~3) + ((cp & 3) ^ (row & 3));
        const float* s = x + (size_t)cidx * 8;
        float4 v0 = *(const float4*)s, v1 = *(const float4*)(s + 4);
        ushort4 a, b;
        a.x = f2h(v0.x); a.y = f2h(v0.y); a.z = f2h(v0.z); a.w = f2h(v0.w);
        b.x = f2h(v1.x); b.y = f2h(v1.y); b.z = f2h(v1.z); b.w = f2h(v1.w);
        unsigned short* d = xb + (size_t)dchunk * 8;
        *(ushort4*)d = a;
        *(ushort4*)(d + 4) = b;
    } else {
        int t = pid - 3072;
        int z = t / 144, r = t - z * 144;
        int kx = r / 12, ny = r - kx * 12;
        const float* src = (z == 0) ? w0 : (z == 1) ? w1 : (z == 2) ? w2 : w3;
        unsigned short* dst = wt + (size_t)z * NW;
        const int k0 = kx * 64, n0 = ny * 64;
        const int tid = threadIdx.x;
        {
            int rowb = tid >> 4, c4 = (tid & 15) * 4;
#pragma unroll
            for (int i = 0; i < 4; ++i) {
                int row = rowb + i * 16;
                float4 v = *(const float4*)&src[(size_t)(k0 + row) * C_DIM + n0 + c4];
                T[row][c4] = v.x; T[row][c4 + 1] = v.y; T[row][c4 + 2] = v.z; T[row][c4 + 3] = v.w;
            }
        }
        __syncthreads();
        {
            int n = tid & 63, kseg = (tid >> 6) * 16;
            int n_glob = n0 + n;
            unsigned short tmp[16];
#pragma unroll
            for (int j = 0; j < 16; ++j) tmp[j] = f2h(T[kseg + j][n]);
            int base = k0 + (kseg & 32);
            int sub = (kseg >> 3) & 3;
            unsigned short* drow = dst + (size_t)n_glob * C_DIM + base;
            *(uint4*)&drow[(sub ^ (n_glob & 3)) << 3]       = *(uint4*)&tmp[0];
            *(uint4*)&drow[((sub + 1) ^ (n_glob & 3)) << 3] = *(uint4*)&tmp[8];
        }
    }
}

// ---------------- QKV GEMM v4: 128x128, BK=64, single-buffer, 5 blocks/CU ----------------
// Rounds 8/9 proved source-level pipelining of the 2-barrier loop is a dead end
// (BK=32 + __syncthreads: 60us; + counted vmcnt/raw barriers: 57us; original
// BK=64: 53us). Reverted to the BK=64 body. New lever: residency. Grid 1152 =
// 4.5 blocks/CU but launch_bounds(256,4) capped residency at 4, leaving a
// 128-block ragged tail. VGPR=60 (<=64) and LDS=32KB allow 5 blocks/CU
// (5x32KB = 160KB exactly, 20 waves/CU) -> whole grid co-resident, no tail,
// +25% waves to hide the barrier drain.
__global__ __launch_bounds__(256, 5)
void qkv_gemm(const unsigned short* __restrict__ xb,
              const unsigned short* __restrict__ wt,
              unsigned short* __restrict__ q_ws,
              unsigned short* __restrict__ k_ws,
              unsigned short* __restrict__ vt_ws) {
    const int pid = blockIdx.x;
    const int xcd = pid & 7, idx = pid >> 3;
    const int mloc = idx / 18, nw = idx - mloc * 18;
    const int which = nw % 3, nx = nw / 3;
    const unsigned short* W = wt + (size_t)which * NW;
    const int n0 = nx * 128, m0 = (xcd * 8 + mloc) * 128;

    __shared__ __align__(16) unsigned short As[8192];
    __shared__ __align__(16) unsigned short Bs[8192];

    const int tid = threadIdx.x, lane = tid & 63, w = tid >> 6;
    const int quad = lane >> 4, l16 = lane & 15;
    const int wm = (w >> 1) * 64, wn = (w & 1) * 64;

    f32x4 acc[4][4] = {};

    for (int k0 = 0; k0 < C_DIM; k0 += 64) {
        __syncthreads();
#pragma unroll
        for (int c = 0; c < 4; ++c) {
            int e = c * 256 + tid;
            int p = e >> 9, row = (e >> 2) & 127, ch = e & 3;
            int kc = k0 + p * 32 + ch * 8;
            gld16(xb + (size_t)(m0 + row) * C_DIM + kc, &As[e * 8]);
            gld16(W  + (size_t)(n0 + row) * C_DIM + kc, &Bs[e * 8]);
        }
        __syncthreads();
#pragma unroll
        for (int p = 0; p < 2; ++p) {
            f16x8 af[4], bf[4];
#pragma unroll
            for (int mt = 0; mt < 4; ++mt) {
                int r = wm + mt * 16 + l16;
                af[mt] = *(const f16x8*)&As[p * 4096 + r * 32 + ((quad ^ (r & 3)) << 3)];
            }
#pragma unroll
            for (int nt = 0; nt < 4; ++nt) {
                int r = wn + nt * 16 + l16;
                bf[nt] = *(const f16x8*)&Bs[p * 4096 + r * 32 + ((quad ^ (r & 3)) << 3)];
            }
            __builtin_amdgcn_s_setprio(1);
#pragma unroll
            for (int mt = 0; mt < 4; ++mt)
#pragma unroll
                for (int nt = 0; nt < 4; ++nt)
                    acc[mt][nt] = __builtin_amdgcn_mfma_f32_16x16x32_f16(af[mt], bf[nt], acc[mt][nt], 0, 0, 0);
            __builtin_amdgcn_s_setprio(0);
        }
    }

    const int head = nx * 2 + (w & 1);

    if (which < 2) {
        unsigned short* dst = (which == 0) ? q_ws : k_ws;
        const float qscale = 0.18033688011112042f;   // 1/8 * log2(e)
#pragma unroll
        for (int ntp = 0; ntp < 2; ++ntp) {
            int d1 = ntp * 16 + l16;
            float invf = __expf(-0.28782313662425572f * (float)d1);
#pragma unroll
            for (int mt = 0; mt < 4; ++mt)
#pragma unroll
                for (int reg = 0; reg < 4; ++reg) {
                    int m = m0 + wm + mt * 16 + quad * 4 + reg;
                    int t = m & (T_SEQ - 1), bb = m >> 11;
                    float sn, cs;
                    __sincosf((float)t * invf, &sn, &cs);
                    float v1 = acc[mt][ntp][reg], v2 = acc[mt][ntp + 2][reg];
                    float o1 = v1 * cs - v2 * sn;
                    float o2 = v2 * cs + v1 * sn;
                    if (which == 0) { o1 *= qscale; o2 *= qscale; }
                    size_t o = ((size_t)(bb * H_NUM + head) * T_SEQ + t) * 64 + d1;
                    dst[o] = f2h(o1);
                    dst[o + 32] = f2h(o2);
                }
        }
    } else {
#pragma unroll
        for (int nt = 0; nt < 4; ++nt) {
            int d = nt * 16 + l16;
#pragma unroll
            for (int mt = 0; mt < 4; ++mt) {
                int m = m0 + wm + mt * 16 + quad * 4;
                int t = m & (T_SEQ - 1), bb = m >> 11;
                ushort4 pk;
                pk.x = f2h(acc[mt][nt][0]); pk.y = f2h(acc[mt][nt][1]);
                pk.z = f2h(acc[mt][nt][2]); pk.w = f2h(acc[mt][nt][3]);
                *(ushort4*)&vt_ws[((size_t)(bb * H_NUM + head) * 64 + d) * T_SEQ + t] = pk;
            }
        }
    }
}

// ---------------- causal flash attention v7: single-strip blocks, 5/CU ----------------
// (unchanged: 51.9us, MfmaUtil 33, Occupancy 35)
__global__ __launch_bounds__(256, 5)
void flash_attn(const unsigned short* __restrict__ q_ws,
                const unsigned short* __restrict__ k_ws,
                const unsigned short* __restrict__ vt_ws,
                unsigned short* __restrict__ attn_out) {   // [B][T][C] f16 plain
    __shared__ __align__(16) unsigned short Kbuf[2][64 * 64];
    __shared__ __align__(16) unsigned short Vbuf[2][64 * 64];

    const int pid = blockIdx.x;
    const int xcd = pid & 7, slot = pid >> 3;   // 0..191 per XCD
    const int sdiv = slot / 6;                  // 0..31
    const int strip = 31 - sdiv;                // LPT: longest strips dispatched first
    const int bh = xcd * 6 + (slot - sdiv * 6);
    const int b = bh / H_NUM, h = bh % H_NUM;

    const int tid = threadIdx.x, lane = tid & 63, w = tid >> 6;
    const int quad = lane >> 4, l16 = lane & 15;
    const size_t base = (size_t)bh * (T_SEQ * 64);

    // Q fragment for this strip (MFMA B-operand)
    const unsigned short* qp = q_ws + base + (size_t)(strip * 64 + w * 16 + l16) * 64 + quad * 8;
    f16x8 aq0 = *(const f16x8*)(qp);
    f16x8 aq1 = *(const f16x8*)(qp + 32);

    f32x4 acc[4] = {};     // O^T: row d = ntd*16 + quad*4 + reg, col q = l16
    float lacc = 0.f;      // per-lane partial denom (own k-subset)
    const h2_t ones2 = __builtin_amdgcn_cvt_pkrtz(1.f, 1.f);

    // DMA lane mapping (K/V stage)
    const int r_in = lane >> 3;
    const int cpr = lane & 7;
    const int gch = (cpr ^ r_in) * 8;

#define DMA_KV(P, KT)                                                                  \
    {                                                                                  \
        _Pragma("unroll")                                                              \
        for (int j = 0; j < 2; ++j) {                                                  \
            int row = w * 16 + j * 8 + r_in;                                           \
            gld16(k_ws + base + (size_t)((KT) * 64 + row) * 64 + gch,                  \
                  &Kbuf[P][(w * 16 + j * 8) * 64]);                                    \
            gld16(vt_ws + base + (size_t)row * T_SEQ + (KT) * 64 + gch,                \
                  &Vbuf[P][(w * 16 + j * 8) * 64]);                                    \
        }                                                                              \
    }

    const int fo = (quad ^ (l16 & 7)) << 3;   // K frag-read chunk offset (b128)

    // V^T 16x16x16 A-frag b64 offsets
    const int q1 = quad >> 1, q0 = quad & 1, s7 = l16 & 7;
    int voff[4];
#pragma unroll
    for (int kb = 0; kb < 4; ++kb)
        voff[kb] = (((((kb << 1) | q1) ^ s7) << 3) | (q0 << 2));

    DMA_KV(0, 0);
    for (int kt = 0; kt <= strip; ++kt) {
        const int cur = kt & 1;
        __syncthreads();
        if (kt < strip) DMA_KV(cur ^ 1, kt + 1);

        // K fragments (A-operand)
        f16x8 bk[4][2];
#pragma unroll
        for (int nt = 0; nt < 4; ++nt) {
            const unsigned short* kr = &Kbuf[cur][(nt * 16 + l16) * 64 + fo];
            bk[nt][0] = *(const f16x8*)(kr);
            bk[nt][1] = *(const f16x8*)((const unsigned short*)((size_t)kr ^ 64));
        }

        // S^T = K x Q^T : row k = nt*16+quad*4+reg, col q = l16
        f32x4 s[4] = {};
        __builtin_amdgcn_s_setprio(1);
#pragma unroll
        for (int nt = 0; nt < 4; ++nt) {
            s[nt] = __builtin_amdgcn_mfma_f32_16x16x32_f16(bk[nt][0], aq0, s[nt], 0, 0, 0);
            s[nt] = __builtin_amdgcn_mfma_f32_16x16x32_f16(bk[nt][1], aq1, s[nt], 0, 0, 0);
        }
        __builtin_amdgcn_s_setprio(0);

        // causal mask on transposed S (k > q) — last tile only
        if (kt == strip) {
#pragma unroll
            for (int nt = 0; nt < 4; ++nt)
#pragma unroll
                for (int reg = 0; reg < 4; ++reg)
                    if (nt * 16 + quad * 4 + reg > w * 16 + l16) s[nt][reg] = -1e30f;
        }

        // exp2 -> packed f16 P^T frags (pure registers) + denom via dot2
        f16x4 pb[4];
#pragma unroll
        for (int kb = 0; kb < 4; ++kb) {
            float p0 = fexp2(s[kb][0]), p1 = fexp2(s[kb][1]);
            float p2 = fexp2(s[kb][2]), p3 = fexp2(s[kb][3]);
            h2_t d0 = __builtin_amdgcn_cvt_pkrtz(p0, p1);
            h2_t d1 = __builtin_amdgcn_cvt_pkrtz(p2, p3);
            lacc = dot2acc(d0, ones2, lacc);
            lacc = dot2acc(d1, ones2, lacc);
            pb[kb] = mk4(d0, d1);
        }

        // PV: O^T += V^T x P^T  (16x16x16)
        __builtin_amdgcn_s_setprio(1);
#pragma unroll
        for (int ntd = 0; ntd < 4; ++ntd) {
            const unsigned short* vrow = &Vbuf[cur][(ntd * 16 + l16) * 64];
            f16x4 av0 = *(const f16x4*)(vrow + voff[0]);
            f16x4 av1 = *(const f16x4*)(vrow + voff[1]);
            f16x4 av2 = *(const f16x4*)(vrow + voff[2]);
            f16x4 av3 = *(const f16x4*)(vrow + voff[3]);
            acc[ntd] = __builtin_amdgcn_mfma_f32_16x16x16f16(av0, pb[0], acc[ntd], 0, 0, 0);
            acc[ntd] = __builtin_amdgcn_mfma_f32_16x16x16f16(av1, pb[1], acc[ntd], 0, 0, 0);
            acc[ntd] = __builtin_amdgcn_mfma_f32_16x16x16f16(av2, pb[2], acc[ntd], 0, 0, 0);
            acc[ntd] = __builtin_amdgcn_mfma_f32_16x16x16f16(av3, pb[3], acc[ntd], 0, 0, 0);
        }
        __builtin_amdgcn_s_setprio(0);
    }
#undef DMA_KV

    // denom: reduce partial sums across the 4 quads
    lacc += __shfl_xor(lacc, 16);
    lacc += __shfl_xor(lacc, 32);
    const float r = 1.0f / lacc;

    // store O^T: lane l16 = t (within strip), d = ntd*16 + quad*4 + reg -> ushort4
    const int t = strip * 64 + w * 16 + l16;
#pragma unroll
    for (int ntd = 0; ntd < 4; ++ntd) {
        int col = h * 64 + ntd * 16 + quad * 4;
        ushort4 pk;
        pk.x = f2h(acc[ntd][0] * r); pk.y = f2h(acc[ntd][1] * r);
        pk.z = f2h(acc[ntd][2] * r); pk.w = f2h(acc[ntd][3] * r);
        *(ushort4*)&attn_out[(size_t)(b * T_SEQ + t) * C_DIM + col] = pk;
    }
}

// ---------------- output projection v2: 128x64 tiles, BK=64 ----------------
// 768 blocks = 3/CU (XCD-uniform), LDS 24KB
__global__ __launch_bounds__(256, 4)
void out_proj(const unsigned short* __restrict__ ab,
              const unsigned short* __restrict__ wt_o,
              float* __restrict__ out) {
    const int pid = blockIdx.x;
    const int xcd = pid & 7, idx = pid >> 3;
    const int mloc = idx / 12, nx = idx - mloc * 12;
    const int n0 = nx * 64, m0 = (xcd * 8 + mloc) * 128;

    __shared__ __align__(16) unsigned short As[8192];
    __shared__ __align__(16) unsigned short Bs[4096];

    const int tid = threadIdx.x, lane = tid & 63, w = tid >> 6;
    const int quad = lane >> 4, l16 = lane & 15;
    const int wm = w * 32;   // wave covers 32 rows x 64 cols

    f32x4 acc[2][4] = {};
    const int srow = tid >> 1, shalf = tid & 1;

    for (int k0 = 0; k0 < C_DIM; k0 += 64) {
        __syncthreads();
#pragma unroll
        for (int p = 0; p < 2; ++p) {
            const unsigned short* g = ab + (size_t)(m0 + srow) * C_DIM + k0 + p * 32 + shalf * 16;
            uint4 d0 = *(const uint4*)g;
            uint4 d1 = *(const uint4*)(g + 8);
            *(uint4*)&As[p * 4096 + srow * 32 + (((shalf * 2 + 0) ^ (srow & 3)) << 3)] = d0;
            *(uint4*)&As[p * 4096 + srow * 32 + (((shalf * 2 + 1) ^ (srow & 3)) << 3)] = d1;
        }
#pragma unroll
        for (int c = 0; c < 2; ++c) {
            int e = c * 256 + tid;
            int p = e >> 8, row = (e >> 2) & 63, ch = e & 3;
            gld16(wt_o + (size_t)(n0 + row) * C_DIM + k0 + p * 32 + ch * 8, &Bs[e * 8]);
        }
        __syncthreads();
#pragma unroll
        for (int p = 0; p < 2; ++p) {
            f16x8 af[2], bf[4];
#pragma unroll
            for (int mt = 0; mt < 2; ++mt) {
                int r = wm + mt * 16 + l16;
                af[mt] = *(const f16x8*)&As[p * 4096 + r * 32 + ((quad ^ (r & 3)) << 3)];
            }
#pragma unroll
            for (int nt = 0; nt < 4; ++nt) {
                int r = nt * 16 + l16;
                bf[nt] = *(const f16x8*)&Bs[p * 2048 + r * 32 + ((quad ^ (r & 3)) << 3)];
            }
#pragma unroll
            for (int mt = 0; mt < 2; ++mt)
#pragma unroll
                for (int nt = 0; nt < 4; ++nt)
                    acc[mt][nt] = __builtin_amdgcn_mfma_f32_16x16x32_f16(af[mt], bf[nt], acc[mt][nt], 0, 0, 0);
        }
    }

#pragma unroll
    for (int mt = 0; mt < 2; ++mt)
#pragma unroll
        for (int nt = 0; nt < 4; ++nt)
#pragma unroll
            for (int reg = 0; reg < 4; ++reg) {
                int m = m0 + wm + mt * 16 + quad * 4 + reg;
                int n = n0 + nt * 16 + l16;
                out[(size_t)m * C_DIM + n] = acc[mt][nt][reg];
            }
}

// ---------------- launch ----------------
extern "C" void kernel_launch(void* const* d_in, const int* in_sizes, int n_in,
                              void* d_out, int out_size, void* d_ws, size_t ws_size,
                              hipStream_t stream) {
    const float* x  = (const float*)d_in[0];
    const float* wq = (const float*)d_in[1];
    const float* wk = (const float*)d_in[2];
    const float* wv = (const float*)d_in[3];
    const float* wo = (const float*)d_in[4];
    float* out = (float*)d_out;

    unsigned short* xb    = (unsigned short*)d_ws;   // NX (swizzled); reused as attn
    unsigned short* wt    = xb + NX;                 // 4*NW swizzled [n][k]
    unsigned short* q_ws  = wt + 4 * (size_t)NW;     // NX
    unsigned short* k_ws  = q_ws + NX;               // NX
    unsigned short* vt_ws = k_ws + NX;               // NX
    unsigned short* attn  = xb;                      // alias: xb dead after qkv_gemm

    prep<<<3648, 256, 0, stream>>>(x, wq, wk, wv, wo, xb, wt);
    qkv_gemm<<<1152, 256, 0, stream>>>(xb, wt, q_ws, k_ws, vt_ws);
    flash_attn<<<1536, 256, 0, stream>>>(q_ws, k_ws, vt_ws, attn);
    out_proj<<<768, 256, 0, stream>>>(attn, wt + 3 * (size_t)NW, out);
}

// Round 11
// 209.165 us; speedup vs baseline: 1.4624x; 1.4624x over previous
//
#include <hip/hip_runtime.h>
#include <hip/hip_bf16.h>
#include <cmath>

typedef _Float16 f16x8 __attribute__((ext_vector_type(8)));
typedef _Float16 f16x4 __attribute__((ext_vector_type(4)));
typedef float f32x4 __attribute__((ext_vector_type(4)));
using h2_t = decltype(__builtin_amdgcn_cvt_pkrtz(0.f, 0.f));

#define T_SEQ 2048
#define C_DIM 768
#define H_NUM 12
#define NX (8192 * 768)
#define NW (768 * 768)

__device__ __forceinline__ unsigned short f2h(float f) {
    _Float16 h = (_Float16)f;
    return __builtin_bit_cast(unsigned short, h);
}

__device__ __forceinline__ float fexp2(float x) {
#if __has_builtin(__builtin_amdgcn_exp2f)
    return __builtin_amdgcn_exp2f(x);
#else
    return exp2f(x);
#endif
}

// build f16x4 from two packed half2
__device__ __forceinline__ f16x4 mk4(h2_t a, h2_t b) {
    uint2 u;
    u.x = __builtin_bit_cast(unsigned int, a);
    u.y = __builtin_bit_cast(unsigned int, b);
    return __builtin_bit_cast(f16x4, u);
}

// acc += d[0]*o[0] + d[1]*o[1]  (f16 mul, f32 acc) — softmax denom with SAME
// rounding as the PV numerator (sums the f16-rounded P values)
__device__ __forceinline__ float dot2acc(h2_t d, h2_t o, float acc) {
#if __has_builtin(__builtin_amdgcn_fdot2)
    return __builtin_amdgcn_fdot2(d, o, acc, false);
#else
    return acc + (float)d[0] + (float)d[1];
#endif
}

// async global->LDS 16B DMA
__device__ __forceinline__ void gld16(const unsigned short* g, unsigned short* l) {
    __builtin_amdgcn_global_load_lds(
        (const __attribute__((address_space(1))) unsigned int*)g,
        (__attribute__((address_space(3))) unsigned int*)l, 16, 0, 0);
}

// ---------------- prep: cast x (swizzled) + transpose-cast 4 weights ----------------
__global__ __launch_bounds__(256)
void prep(const float* __restrict__ x,
          const float* __restrict__ w0, const float* __restrict__ w1,
          const float* __restrict__ w2, const float* __restrict__ w3,
          unsigned short* __restrict__ xb, unsigned short* __restrict__ wt) {
    __shared__ float T[64][65];
    const int pid = blockIdx.x;
    if (pid < 3072) {
        int cidx = pid * 256 + threadIdx.x;
        int row = cidx / 96;
        int cp = cidx - row * 96;
        int dchunk = row * 96 + (cp & ~3) + ((cp & 3) ^ (row & 3));
        const float* s = x + (size_t)cidx * 8;
        float4 v0 = *(const float4*)s, v1 = *(const float4*)(s + 4);
        ushort4 a, b;
        a.x = f2h(v0.x); a.y = f2h(v0.y); a.z = f2h(v0.z); a.w = f2h(v0.w);
        b.x = f2h(v1.x); b.y = f2h(v1.y); b.z = f2h(v1.z); b.w = f2h(v1.w);
        unsigned short* d = xb + (size_t)dchunk * 8;
        *(ushort4*)d = a;
        *(ushort4*)(d + 4) = b;
    } else {
        int t = pid - 3072;
        int z = t / 144, r = t - z * 144;
        int kx = r / 12, ny = r - kx * 12;
        const float* src = (z == 0) ? w0 : (z == 1) ? w1 : (z == 2) ? w2 : w3;
        unsigned short* dst = wt + (size_t)z * NW;
        const int k0 = kx * 64, n0 = ny * 64;
        const int tid = threadIdx.x;
        {
            int rowb = tid >> 4, c4 = (tid & 15) * 4;
#pragma unroll
            for (int i = 0; i < 4; ++i) {
                int row = rowb + i * 16;
                float4 v = *(const float4*)&src[(size_t)(k0 + row) * C_DIM + n0 + c4];
                T[row][c4] = v.x; T[row][c4 + 1] = v.y; T[row][c4 + 2] = v.z; T[row][c4 + 3] = v.w;
            }
        }
        __syncthreads();
        {
            int n = tid & 63, kseg = (tid >> 6) * 16;
            int n_glob = n0 + n;
            unsigned short tmp[16];
#pragma unroll
            for (int j = 0; j < 16; ++j) tmp[j] = f2h(T[kseg + j][n]);
            int base = k0 + (kseg & 32);
            int sub = (kseg >> 3) & 3;
            unsigned short* drow = dst + (size_t)n_glob * C_DIM + base;
            *(uint4*)&drow[(sub ^ (n_glob & 3)) << 3]       = *(uint4*)&tmp[0];
            *(uint4*)&drow[((sub + 1) ^ (n_glob & 3)) << 3] = *(uint4*)&tmp[8];
        }
    }
}

// ---------------- QKV GEMM: 128x128, BK=64, single-buffer, 4 blocks/CU ----------------
// RESTORED to the round-7 verified best (53.3us). Session evidence:
//   BK=32 + __syncthreads dbuf:       60.1us (barrier drains the prefetch)
//   BK=32 + counted vmcnt/raw barrier: 57.2us (compute/barrier ratio halved)
//   lb(256,5) residency push:         156us  (VGPR cap 96 -> acc spilled, WRITE 222MB)
// The 2-barrier BK=64 loop at 4 blocks/CU is the local optimum; passing it
// requires the full 8-phase counted-vmcnt schedule (co-designed rewrite).
__global__ __launch_bounds__(256, 4)
void qkv_gemm(const unsigned short* __restrict__ xb,
              const unsigned short* __restrict__ wt,
              unsigned short* __restrict__ q_ws,
              unsigned short* __restrict__ k_ws,
              unsigned short* __restrict__ vt_ws) {
    const int pid = blockIdx.x;
    const int xcd = pid & 7, idx = pid >> 3;
    const int mloc = idx / 18, nw = idx - mloc * 18;
    const int which = nw % 3, nx = nw / 3;
    const unsigned short* W = wt + (size_t)which * NW;
    const int n0 = nx * 128, m0 = (xcd * 8 + mloc) * 128;

    __shared__ __align__(16) unsigned short As[8192];
    __shared__ __align__(16) unsigned short Bs[8192];

    const int tid = threadIdx.x, lane = tid & 63, w = tid >> 6;
    const int quad = lane >> 4, l16 = lane & 15;
    const int wm = (w >> 1) * 64, wn = (w & 1) * 64;

    f32x4 acc[4][4] = {};

    for (int k0 = 0; k0 < C_DIM; k0 += 64) {
        __syncthreads();
#pragma unroll
        for (int c = 0; c < 4; ++c) {
            int e = c * 256 + tid;
            int p = e >> 9, row = (e >> 2) & 127, ch = e & 3;
            int kc = k0 + p * 32 + ch * 8;
            gld16(xb + (size_t)(m0 + row) * C_DIM + kc, &As[e * 8]);
            gld16(W  + (size_t)(n0 + row) * C_DIM + kc, &Bs[e * 8]);
        }
        __syncthreads();
#pragma unroll
        for (int p = 0; p < 2; ++p) {
            f16x8 af[4], bf[4];
#pragma unroll
            for (int mt = 0; mt < 4; ++mt) {
                int r = wm + mt * 16 + l16;
                af[mt] = *(const f16x8*)&As[p * 4096 + r * 32 + ((quad ^ (r & 3)) << 3)];
            }
#pragma unroll
            for (int nt = 0; nt < 4; ++nt) {
                int r = wn + nt * 16 + l16;
                bf[nt] = *(const f16x8*)&Bs[p * 4096 + r * 32 + ((quad ^ (r & 3)) << 3)];
            }
#pragma unroll
            for (int mt = 0; mt < 4; ++mt)
#pragma unroll
                for (int nt = 0; nt < 4; ++nt)
                    acc[mt][nt] = __builtin_amdgcn_mfma_f32_16x16x32_f16(af[mt], bf[nt], acc[mt][nt], 0, 0, 0);
        }
    }

    const int head = nx * 2 + (w & 1);

    if (which < 2) {
        unsigned short* dst = (which == 0) ? q_ws : k_ws;
        const float qscale = 0.18033688011112042f;   // 1/8 * log2(e)
#pragma unroll
        for (int ntp = 0; ntp < 2; ++ntp) {
            int d1 = ntp * 16 + l16;
            float invf = __expf(-0.28782313662425572f * (float)d1);
#pragma unroll
            for (int mt = 0; mt < 4; ++mt)
#pragma unroll
                for (int reg = 0; reg < 4; ++reg) {
                    int m = m0 + wm + mt * 16 + quad * 4 + reg;
                    int t = m & (T_SEQ - 1), bb = m >> 11;
                    float sn, cs;
                    __sincosf((float)t * invf, &sn, &cs);
                    float v1 = acc[mt][ntp][reg], v2 = acc[mt][ntp + 2][reg];
                    float o1 = v1 * cs - v2 * sn;
                    float o2 = v2 * cs + v1 * sn;
                    if (which == 0) { o1 *= qscale; o2 *= qscale; }
                    size_t o = ((size_t)(bb * H_NUM + head) * T_SEQ + t) * 64 + d1;
                    dst[o] = f2h(o1);
                    dst[o + 32] = f2h(o2);
                }
        }
    } else {
#pragma unroll
        for (int nt = 0; nt < 4; ++nt) {
            int d = nt * 16 + l16;
#pragma unroll
            for (int mt = 0; mt < 4; ++mt) {
                int m = m0 + wm + mt * 16 + quad * 4;
                int t = m & (T_SEQ - 1), bb = m >> 11;
                ushort4 pk;
                pk.x = f2h(acc[mt][nt][0]); pk.y = f2h(acc[mt][nt][1]);
                pk.z = f2h(acc[mt][nt][2]); pk.w = f2h(acc[mt][nt][3]);
                *(ushort4*)&vt_ws[((size_t)(bb * H_NUM + head) * 64 + d) * T_SEQ + t] = pk;
            }
        }
    }
}

// ---------------- causal flash attention v7: single-strip blocks, 5/CU ----------------
// (verified: 51.9us, MfmaUtil 33, Occupancy 35)
__global__ __launch_bounds__(256, 5)
void flash_attn(const unsigned short* __restrict__ q_ws,
                const unsigned short* __restrict__ k_ws,
                const unsigned short* __restrict__ vt_ws,
                unsigned short* __restrict__ attn_out) {   // [B][T][C] f16 plain
    __shared__ __align__(16) unsigned short Kbuf[2][64 * 64];
    __shared__ __align__(16) unsigned short Vbuf[2][64 * 64];

    const int pid = blockIdx.x;
    const int xcd = pid & 7, slot = pid >> 3;   // 0..191 per XCD
    const int sdiv = slot / 6;                  // 0..31
    const int strip = 31 - sdiv;                // LPT: longest strips dispatched first
    const int bh = xcd * 6 + (slot - sdiv * 6);
    const int b = bh / H_NUM, h = bh % H_NUM;

    const int tid = threadIdx.x, lane = tid & 63, w = tid >> 6;
    const int quad = lane >> 4, l16 = lane & 15;
    const size_t base = (size_t)bh * (T_SEQ * 64);

    // Q fragment for this strip (MFMA B-operand)
    const unsigned short* qp = q_ws + base + (size_t)(strip * 64 + w * 16 + l16) * 64 + quad * 8;
    f16x8 aq0 = *(const f16x8*)(qp);
    f16x8 aq1 = *(const f16x8*)(qp + 32);

    f32x4 acc[4] = {};     // O^T: row d = ntd*16 + quad*4 + reg, col q = l16
    float lacc = 0.f;      // per-lane partial denom (own k-subset)
    const h2_t ones2 = __builtin_amdgcn_cvt_pkrtz(1.f, 1.f);

    // DMA lane mapping (K/V stage)
    const int r_in = lane >> 3;
    const int cpr = lane & 7;
    const int gch = (cpr ^ r_in) * 8;

#define DMA_KV(P, KT)                                                                  \
    {                                                                                  \
        _Pragma("unroll")                                                              \
        for (int j = 0; j < 2; ++j) {                                                  \
            int row = w * 16 + j * 8 + r_in;                                           \
            gld16(k_ws + base + (size_t)((KT) * 64 + row) * 64 + gch,                  \
                  &Kbuf[P][(w * 16 + j * 8) * 64]);                                    \
            gld16(vt_ws + base + (size_t)row * T_SEQ + (KT) * 64 + gch,                \
                  &Vbuf[P][(w * 16 + j * 8) * 64]);                                    \
        }                                                                              \
    }

    const int fo = (quad ^ (l16 & 7)) << 3;   // K frag-read chunk offset (b128)

    // V^T 16x16x16 A-frag b64 offsets
    const int q1 = quad >> 1, q0 = quad & 1, s7 = l16 & 7;
    int voff[4];
#pragma unroll
    for (int kb = 0; kb < 4; ++kb)
        voff[kb] = (((((kb << 1) | q1) ^ s7) << 3) | (q0 << 2));

    DMA_KV(0, 0);
    for (int kt = 0; kt <= strip; ++kt) {
        const int cur = kt & 1;
        __syncthreads();
        if (kt < strip) DMA_KV(cur ^ 1, kt + 1);

        // K fragments (A-operand)
        f16x8 bk[4][2];
#pragma unroll
        for (int nt = 0; nt < 4; ++nt) {
            const unsigned short* kr = &Kbuf[cur][(nt * 16 + l16) * 64 + fo];
            bk[nt][0] = *(const f16x8*)(kr);
            bk[nt][1] = *(const f16x8*)((const unsigned short*)((size_t)kr ^ 64));
        }

        // S^T = K x Q^T : row k = nt*16+quad*4+reg, col q = l16
        f32x4 s[4] = {};
        __builtin_amdgcn_s_setprio(1);
#pragma unroll
        for (int nt = 0; nt < 4; ++nt) {
            s[nt] = __builtin_amdgcn_mfma_f32_16x16x32_f16(bk[nt][0], aq0, s[nt], 0, 0, 0);
            s[nt] = __builtin_amdgcn_mfma_f32_16x16x32_f16(bk[nt][1], aq1, s[nt], 0, 0, 0);
        }
        __builtin_amdgcn_s_setprio(0);

        // causal mask on transposed S (k > q) — last tile only
        if (kt == strip) {
#pragma unroll
            for (int nt = 0; nt < 4; ++nt)
#pragma unroll
                for (int reg = 0; reg < 4; ++reg)
                    if (nt * 16 + quad * 4 + reg > w * 16 + l16) s[nt][reg] = -1e30f;
        }

        // exp2 -> packed f16 P^T frags (pure registers) + denom via dot2
        f16x4 pb[4];
#pragma unroll
        for (int kb = 0; kb < 4; ++kb) {
            float p0 = fexp2(s[kb][0]), p1 = fexp2(s[kb][1]);
            float p2 = fexp2(s[kb][2]), p3 = fexp2(s[kb][3]);
            h2_t d0 = __builtin_amdgcn_cvt_pkrtz(p0, p1);
            h2_t d1 = __builtin_amdgcn_cvt_pkrtz(p2, p3);
            lacc = dot2acc(d0, ones2, lacc);
            lacc = dot2acc(d1, ones2, lacc);
            pb[kb] = mk4(d0, d1);
        }

        // PV: O^T += V^T x P^T  (16x16x16)
        __builtin_amdgcn_s_setprio(1);
#pragma unroll
        for (int ntd = 0; ntd < 4; ++ntd) {
            const unsigned short* vrow = &Vbuf[cur][(ntd * 16 + l16) * 64];
            f16x4 av0 = *(const f16x4*)(vrow + voff[0]);
            f16x4 av1 = *(const f16x4*)(vrow + voff[1]);
            f16x4 av2 = *(const f16x4*)(vrow + voff[2]);
            f16x4 av3 = *(const f16x4*)(vrow + voff[3]);
            acc[ntd] = __builtin_amdgcn_mfma_f32_16x16x16f16(av0, pb[0], acc[ntd], 0, 0, 0);
            acc[ntd] = __builtin_amdgcn_mfma_f32_16x16x16f16(av1, pb[1], acc[ntd], 0, 0, 0);
            acc[ntd] = __builtin_amdgcn_mfma_f32_16x16x16f16(av2, pb[2], acc[ntd], 0, 0, 0);
            acc[ntd] = __builtin_amdgcn_mfma_f32_16x16x16f16(av3, pb[3], acc[ntd], 0, 0, 0);
        }
        __builtin_amdgcn_s_setprio(0);
    }
#undef DMA_KV

    // denom: reduce partial sums across the 4 quads
    lacc += __shfl_xor(lacc, 16);
    lacc += __shfl_xor(lacc, 32);
    const float r = 1.0f / lacc;

    // store O^T: lane l16 = t (within strip), d = ntd*16 + quad*4 + reg -> ushort4
    const int t = strip * 64 + w * 16 + l16;
#pragma unroll
    for (int ntd = 0; ntd < 4; ++ntd) {
        int col = h * 64 + ntd * 16 + quad * 4;
        ushort4 pk;
        pk.x = f2h(acc[ntd][0] * r); pk.y = f2h(acc[ntd][1] * r);
        pk.z = f2h(acc[ntd][2] * r); pk.w = f2h(acc[ntd][3] * r);
        *(ushort4*)&attn_out[(size_t)(b * T_SEQ + t) * C_DIM + col] = pk;
    }
}

// ---------------- output projection v2: 128x64 tiles, BK=64 ----------------
// 768 blocks = 3/CU (XCD-uniform), LDS 24KB
__global__ __launch_bounds__(256, 4)
void out_proj(const unsigned short* __restrict__ ab,
              const unsigned short* __restrict__ wt_o,
              float* __restrict__ out) {
    const int pid = blockIdx.x;
    const int xcd = pid & 7, idx = pid >> 3;
    const int mloc = idx / 12, nx = idx - mloc * 12;
    const int n0 = nx * 64, m0 = (xcd * 8 + mloc) * 128;

    __shared__ __align__(16) unsigned short As[8192];
    __shared__ __align__(16) unsigned short Bs[4096];

    const int tid = threadIdx.x, lane = tid & 63, w = tid >> 6;
    const int quad = lane >> 4, l16 = lane & 15;
    const int wm = w * 32;   // wave covers 32 rows x 64 cols

    f32x4 acc[2][4] = {};
    const int srow = tid >> 1, shalf = tid & 1;

    for (int k0 = 0; k0 < C_DIM; k0 += 64) {
        __syncthreads();
#pragma unroll
        for (int p = 0; p < 2; ++p) {
            const unsigned short* g = ab + (size_t)(m0 + srow) * C_DIM + k0 + p * 32 + shalf * 16;
            uint4 d0 = *(const uint4*)g;
            uint4 d1 = *(const uint4*)(g + 8);
            *(uint4*)&As[p * 4096 + srow * 32 + (((shalf * 2 + 0) ^ (srow & 3)) << 3)] = d0;
            *(uint4*)&As[p * 4096 + srow * 32 + (((shalf * 2 + 1) ^ (srow & 3)) << 3)] = d1;
        }
#pragma unroll
        for (int c = 0; c < 2; ++c) {
            int e = c * 256 + tid;
            int p = e >> 8, row = (e >> 2) & 63, ch = e & 3;
            gld16(wt_o + (size_t)(n0 + row) * C_DIM + k0 + p * 32 + ch * 8, &Bs[e * 8]);
        }
        __syncthreads();
#pragma unroll
        for (int p = 0; p < 2; ++p) {
            f16x8 af[2], bf[4];
#pragma unroll
            for (int mt = 0; mt < 2; ++mt) {
                int r = wm + mt * 16 + l16;
                af[mt] = *(const f16x8*)&As[p * 4096 + r * 32 + ((quad ^ (r & 3)) << 3)];
            }
#pragma unroll
            for (int nt = 0; nt < 4; ++nt) {
                int r = nt * 16 + l16;
                bf[nt] = *(const f16x8*)&Bs[p * 2048 + r * 32 + ((quad ^ (r & 3)) << 3)];
            }
#pragma unroll
            for (int mt = 0; mt < 2; ++mt)
#pragma unroll
                for (int nt = 0; nt < 4; ++nt)
                    acc[mt][nt] = __builtin_amdgcn_mfma_f32_16x16x32_f16(af[mt], bf[nt], acc[mt][nt], 0, 0, 0);
        }
    }

#pragma unroll
    for (int mt = 0; mt < 2; ++mt)
#pragma unroll
        for (int nt = 0; nt < 4; ++nt)
#pragma unroll
            for (int reg = 0; reg < 4; ++reg) {
                int m = m0 + wm + mt * 16 + quad * 4 + reg;
                int n = n0 + nt * 16 + l16;
                out[(size_t)m * C_DIM + n] = acc[mt][nt][reg];
            }
}

// ---------------- launch ----------------
extern "C" void kernel_launch(void* const* d_in, const int* in_sizes, int n_in,
                              void* d_out, int out_size, void* d_ws, size_t ws_size,
                              hipStream_t stream) {
    const float* x  = (const float*)d_in[0];
    const float* wq = (const float*)d_in[1];
    const float* wk = (const float*)d_in[2];
    const float* wv = (const float*)d_in[3];
    const float* wo = (const float*)d_in[4];
    float* out = (float*)d_out;

    unsigned short* xb    = (unsigned short*)d_ws;   // NX (swizzled); reused as attn
    unsigned short* wt    = xb + NX;                 // 4*NW swizzled [n][k]
    unsigned short* q_ws  = wt + 4 * (size_t)NW;     // NX
    unsigned short* k_ws  = q_ws + NX;               // NX
    unsigned short* vt_ws = k_ws + NX;               // NX
    unsigned short* attn  = xb;                      // alias: xb dead after qkv_gemm

    prep<<<3648, 256, 0, stream>>>(x, wq, wk, wv, wo, xb, wt);
    qkv_gemm<<<1152, 256, 0, stream>>>(xb, wt, q_ws, k_ws, vt_ws);
    flash_attn<<<1536, 256, 0, stream>>>(q_ws, k_ws, vt_ws, attn);
    out_proj<<<768, 256, 0, stream>>>(attn, wt + 3 * (size_t)NW, out);
}